// Round 9
// baseline (199.542 us; speedup 1.0000x reference)
//
#include <hip/hip_runtime.h>
#include <hip/hip_bf16.h>

// Problem constants (B=2,T=64,N=64,D_IN=512,HID=256,L=2,H=4,C=64)
#define BT_G   128
#define NND    64
#define D_IN_  512
#define HID_   256
#define NH     4
#define NCH    64
#define NROWS  8192
#define LN_EPS_    1e-5f

typedef __hip_bfloat16 bf16;
typedef __attribute__((ext_vector_type(8))) short short8;   // 8 bf16 = 4 VGPRs
typedef __attribute__((ext_vector_type(4))) float float4v;  // MFMA C/D

// ---------------------------------------------------------------------------
// Dispatch 1 (heterogeneous, 769 blocks):
//   bid <  512 : input GEMM h0 = x @ W_in^T + b_in (64x64 tile, BK=128),
//                transposing W_in tiles in-staging (no WTin buffer).
//   bid <  768 : Wl/Wr -> WlrT transposes (consumed by later dispatches).
//   bid == 768 : mask canonicalize -> mcan.
union PrepArena {
    float t[32][33];
    struct { bf16 As[64 * 136]; bf16 Bs[64 * 136]; } g;   // BK=128, 34.8 KB
    int flags[4];
};

__global__ __launch_bounds__(256) void prep_gemm_in_kernel(
    const float* __restrict__ x, const unsigned* __restrict__ mw,
    const float* __restrict__ W_in, const float* __restrict__ b_in,
    const float* __restrict__ Wl, const float* __restrict__ Wr,
    float* __restrict__ Cf, bf16* __restrict__ Cb16,
    bf16* __restrict__ WlrT, int* __restrict__ mout)
{
    __shared__ PrepArena ar;
    const int tid = threadIdx.x;
    const int bid = blockIdx.x;

    if (bid < 512) {
        bf16* As = ar.g.As;
        bf16* Bs = ar.g.Bs;
        const int wave = tid >> 6, lane = tid & 63;
        const int quad = lane >> 4, l16 = lane & 15;
        const int m0 = (bid >> 2) * 64, n0 = (bid & 3) * 64;
        const int wm = (wave & 1) * 32, wn = (wave >> 1) * 32;
        float4v acc[2][2] = {};
        const int r  = tid >> 2;            // 0..63
        const int cq = (tid & 3) * 32;      // 0,32,64,96 within BK=128
        for (int k0 = 0; k0 < D_IN_; k0 += 128) {
            // A: 32 floats/thread (rows r, k = k0+cq .. +31)
            const float* sa = x + (size_t)(m0 + r) * D_IN_ + k0 + cq;
            float fa[32];
            #pragma unroll
            for (int q = 0; q < 8; ++q)
                *(float4*)(fa + 4 * q) = *(const float4*)(sa + 4 * q);
            // B: W_in[k0+cq+j][n0+r] for j=0..31 — read rows, scatter (transpose)
            // Each thread reads 2 rows x 16 cols? No: keep r0 pattern — thread
            // (r, cq) reads W_in rows (k0 + cq..cq+31) col (n0 + r)? strided.
            // Retain verified pattern: read W rows coalesced, scatter 32 elems.
            const float* sw0 = W_in + (size_t)(k0 + (tid >> 3)) * HID_ + n0 + (tid & 7) * 8;
            // thread covers rows (tid>>3) + {0,32,64,96}, 8 cols each
            float wv[4][8];
            #pragma unroll
            for (int q = 0; q < 4; ++q) {
                const float* swq = sw0 + (size_t)(q * 32) * HID_;
                *(float4*)(wv[q])     = *(const float4*)(swq);
                *(float4*)(wv[q] + 4) = *(const float4*)(swq + 4);
            }
            union { bf16 hh[32]; float4 v[4]; } u;
            #pragma unroll
            for (int q = 0; q < 32; ++q) u.hh[q] = __float2bfloat16(fa[q]);
            __syncthreads();
            #pragma unroll
            for (int q = 0; q < 4; ++q)
                *(float4*)(&As[r * 136 + cq + 8 * q]) = u.v[q];
            {
                const int kr = tid >> 3;            // 0..31 base k-row
                const int c8 = (tid & 7) * 8;       // col within tile
                #pragma unroll
                for (int q = 0; q < 4; ++q)
                    #pragma unroll
                    for (int j = 0; j < 8; ++j)
                        Bs[(c8 + j) * 136 + kr + q * 32] = __float2bfloat16(wv[q][j]);
            }
            __syncthreads();
            #pragma unroll
            for (int kk = 0; kk < 128; kk += 32) {
                short8 af[2], bf2[2];
                #pragma unroll
                for (int mi = 0; mi < 2; ++mi)
                    af[mi] = *(const short8*)(&As[(wm + mi * 16 + l16) * 136 + kk + quad * 8]);
                #pragma unroll
                for (int ni = 0; ni < 2; ++ni)
                    bf2[ni] = *(const short8*)(&Bs[(wn + ni * 16 + l16) * 136 + kk + quad * 8]);
                #pragma unroll
                for (int mi = 0; mi < 2; ++mi)
                    #pragma unroll
                    for (int ni = 0; ni < 2; ++ni)
                        acc[mi][ni] = __builtin_amdgcn_mfma_f32_16x16x32_bf16(
                            af[mi], bf2[ni], acc[mi][ni], 0, 0, 0);
            }
        }
        #pragma unroll
        for (int ni = 0; ni < 2; ++ni) {
            const int col = n0 + wn + ni * 16 + l16;
            const float bv = b_in[col];
            #pragma unroll
            for (int mi = 0; mi < 2; ++mi)
                #pragma unroll
                for (int rr = 0; rr < 4; ++rr) {
                    const int row = m0 + wm + mi * 16 + quad * 4 + rr;
                    const float v = acc[mi][ni][rr] + bv;
                    Cf[(size_t)row * HID_ + col] = v;
                    Cb16[(size_t)row * HID_ + col] = __float2bfloat16(v);
                }
        }
    } else if (bid < 768) {
        const int q = bid - 512;
        const int z4 = q >> 6;                 // 0,1: Wl li ; 2,3: Wr li
        const int s = q & 63;
        const int n0 = (s & 7) * 32, k0 = (s >> 3) * 32;
        const float* src = (z4 < 2) ? (Wl + z4 * 65536) : (Wr + (z4 - 2) * 65536);
        bf16* dst = WlrT + ((z4 < 2) ? (size_t)z4 * 131072
                                     : (size_t)(z4 - 2) * 131072 + 65536);
        const int tx = tid & 31, ty = tid >> 5;
        #pragma unroll
        for (int i = 0; i < 4; ++i)
            ar.t[ty + 8 * i][tx] = src[(size_t)(k0 + ty + 8 * i) * 256 + n0 + tx];
        __syncthreads();
        #pragma unroll
        for (int i = 0; i < 4; ++i)
            dst[(size_t)(n0 + ty + 8 * i) * 256 + k0 + tx] =
                __float2bfloat16(ar.t[tx][ty + 8 * i]);
    } else {
        int* fl = ar.flags;
        if (tid == 0) { fl[0] = 1; fl[1] = 1; fl[2] = 1; fl[3] = 1; }
        __syncthreads();
        int aI = 1, aF = 1, aB = 1, aC = 1;
        for (int i = tid; i < 2048; i += 256) {   // 8 KB probe — safe all layouts
            const unsigned w2 = mw[i];
            aI &= (w2 <= 1u);
            aF &= (w2 == 0u || w2 == 0x3F800000u);
            const unsigned lo = w2 & 0xFFFFu, hi = w2 >> 16;
            aB &= ((lo == 0u || lo == 0x3F80u) && (hi == 0u || hi == 0x3F80u));
            aC &= (((w2 | (w2 >> 8) | (w2 >> 16) | (w2 >> 24)) & 0xFEu) == 0u);
        }
        if (!aI) atomicAnd(&fl[0], 0);
        if (!aF) atomicAnd(&fl[1], 0);
        if (!aB) atomicAnd(&fl[2], 0);
        if (!aC) atomicAnd(&fl[3], 0);
        __syncthreads();
        const int layout = (fl[0] || fl[1]) ? 0 : (fl[2] ? 2 : (fl[3] ? 3 : 0));
        for (int i = tid; i < NROWS; i += 256) {
            int v;
            if (layout == 2)      v = (((const unsigned short*)mw)[i] != 0);
            else if (layout == 3) v = (((const unsigned char*)mw)[i] != 0);
            else                  v = (mw[i] != 0u);
            mout[i] = v;
        }
    }
}

// ---------------------------------------------------------------------------
// Fused xl|xr GEMM + GATv2 attention per (head, graph): 512 blocks.
// GEMM: 64 rows x 128 cols (xl head-cols | xr head-cols), K=256, BK=128
// (2 K-iterations, 4 barriers total). acc + bias scattered straight into
// attention LDS layouts — xl/xr never touch global. Then r7-verified
// register-softmax attention (one barrier) writes g.
// C-fragment mapping: row=wm+mi*16+quad*4+rr, col=wn+ni*16+l16.
// Waves 0,1 (wn=0) own xl cols; waves 2,3 (wn=64) own xr.
union FusedArena {
    struct { bf16 As[64 * 136]; bf16 Bs[128 * 136]; } g;          // 52.2 KB
    struct { float xls[64][68], xlsT[64][68], xrsT[64][68]; } a;  // 52.2 KB
};

__global__ __launch_bounds__(256) void gemm_attn_kernel(
    const bf16* __restrict__ hxbA, const bf16* __restrict__ WlrTl,
    const float* __restrict__ bll, const float* __restrict__ brl,
    const float* __restrict__ attl, const int* __restrict__ msk,
    float* __restrict__ g)
{
    __shared__ FusedArena ar;
    __shared__ float av[64];
    __shared__ int   ms[64];

    const int tid  = threadIdx.x;
    const int head = blockIdx.x, gr = blockIdx.y;
    const int wave = tid >> 6, lane = tid & 63;
    const int quad = lane >> 4, l16 = lane & 15;
    const int wm = (wave & 1) * 32;        // row offset (graph node)
    const int wn = (wave >> 1) * 64;       // col offset: 0 = xl, 64 = xr
    float4v acc[2][4] = {};

    // ---- GEMM: C[64][128] = hxb[gr rows][256] @ B^T + bias (BK=128) ------
    {
        bf16* As = ar.g.As;
        bf16* Bs = ar.g.Bs;
        const int rA  = tid >> 2;            // 0..63
        const int cqA = (tid & 3) * 32;
        const int rB  = tid >> 1;            // 0..127
        const int cqB = (tid & 1) * 64;
        // B-panel source row: xl j<64 -> head*64+j ; xr -> 256+head*64+j
        const int srcB = (rB < 64) ? (head * NCH + rB) : (256 + head * NCH + rB - 64);
        for (int k0 = 0; k0 < HID_; k0 += 128) {
            const bf16* sa = hxbA + (size_t)(gr * NND + rA) * HID_ + k0 + cqA;
            float4 a[4];
            #pragma unroll
            for (int q = 0; q < 4; ++q)
                a[q] = *(const float4*)(sa + 8 * q);
            const bf16* sb = WlrTl + (size_t)srcB * HID_ + k0 + cqB;
            float4 b[8];
            #pragma unroll
            for (int q = 0; q < 8; ++q)
                b[q] = *(const float4*)(sb + 8 * q);
            __syncthreads();
            #pragma unroll
            for (int q = 0; q < 4; ++q)
                *(float4*)(&As[rA * 136 + cqA + 8 * q]) = a[q];
            #pragma unroll
            for (int q = 0; q < 8; ++q)
                *(float4*)(&Bs[rB * 136 + cqB + 8 * q]) = b[q];
            __syncthreads();
            #pragma unroll
            for (int kk = 0; kk < 128; kk += 32) {
                short8 af[2], bf2[4];
                #pragma unroll
                for (int mi = 0; mi < 2; ++mi)
                    af[mi] = *(const short8*)(&As[(wm + mi * 16 + l16) * 136 + kk + quad * 8]);
                #pragma unroll
                for (int ni = 0; ni < 4; ++ni)
                    bf2[ni] = *(const short8*)(&Bs[(wn + ni * 16 + l16) * 136 + kk + quad * 8]);
                #pragma unroll
                for (int mi = 0; mi < 2; ++mi)
                    #pragma unroll
                    for (int ni = 0; ni < 4; ++ni)
                        acc[mi][ni] = __builtin_amdgcn_mfma_f32_16x16x32_bf16(
                            af[mi], bf2[ni], acc[mi][ni], 0, 0, 0);
            }
        }
    }
    __syncthreads();   // all As/Bs reads done before arena reuse

    // ---- scatter acc (+bias) into attention layouts ----------------------
    {
        const bool xlW = (wn == 0);
        const float* bp = xlW ? bll : brl;
        float bias[4];
        #pragma unroll
        for (int ni = 0; ni < 4; ++ni)
            bias[ni] = bp[head * NCH + ni * 16 + l16];
        #pragma unroll
        for (int mi = 0; mi < 2; ++mi)
            #pragma unroll
            for (int ni = 0; ni < 4; ++ni)
                #pragma unroll
                for (int rr = 0; rr < 4; ++rr) {
                    const int row = wm + mi * 16 + quad * 4 + rr;   // node
                    const int c   = ni * 16 + l16;                  // channel
                    const float v = acc[mi][ni][rr] + bias[ni];
                    if (xlW) {
                        ar.a.xls[row][c] = v;
                        ar.a.xlsT[c][row] = v;
                    } else {
                        ar.a.xrsT[c][row] = v;
                    }
                }
        if (tid < 64) {
            av[tid] = attl[head * NCH + tid];
            ms[tid] = msk[gr * NND + tid];
        }
    }
    __syncthreads();   // the only attention barrier

    // ---- phase 1: abs-sum + P/Q register accumulation (r7-verified) ------
    const int ti = tid >> 4, tj = tid & 15;   // 16x16 thread grid
    const int i0 = ti * 4, j0 = tj * 4;       // 4x4 tile
    float aa[4][4] = {};
    float p4[4] = {}, q4[4] = {};
    for (int c = 0; c < 64; ++c) {
        const float a = av[c];
        float xr4[4], xl4[4];
        *(float4*)xr4 = *(const float4*)&ar.a.xrsT[c][i0];
        *(float4*)xl4 = *(const float4*)&ar.a.xlsT[c][j0];
        #pragma unroll
        for (int y = 0; y < 4; ++y) p4[y] = fmaf(a, xr4[y], p4[y]);
        #pragma unroll
        for (int x = 0; x < 4; ++x) q4[x] = fmaf(a, xl4[x], q4[x]);
        #pragma unroll
        for (int y = 0; y < 4; ++y)
            #pragma unroll
            for (int x = 0; x < 4; ++x)
                aa[y][x] = fmaf(a, fabsf(xr4[y] + xl4[x]), aa[y][x]);
    }

    // ---- combine + mask + register softmax (16-lane group reductions) ----
    float inv4[4];
    {
        int mi4[4], mj4[4];
        #pragma unroll
        for (int y = 0; y < 4; ++y) mi4[y] = ms[i0 + y];
        #pragma unroll
        for (int x = 0; x < 4; ++x) mj4[x] = ms[j0 + x];
        #pragma unroll
        for (int y = 0; y < 4; ++y) {
            float e[4];
            #pragma unroll
            for (int x = 0; x < 4; ++x) {
                const float ev = fmaf(0.4f, aa[y][x], 0.6f * (p4[y] + q4[x]));
                const bool allowed = (mi4[y] && mj4[x]) || (i0 + y == j0 + x);
                e[x] = allowed ? ev : -1e9f;
            }
            float m = fmaxf(fmaxf(e[0], e[1]), fmaxf(e[2], e[3]));
            #pragma unroll
            for (int off = 1; off < 16; off <<= 1)
                m = fmaxf(m, __shfl_xor(m, off));
            float s = 0.f;
            #pragma unroll
            for (int x = 0; x < 4; ++x) {
                const float ev = __expf(e[x] - m);
                aa[y][x] = ev;            // unnormalized alpha stays in regs
                s += ev;
            }
            #pragma unroll
            for (int off = 1; off < 16; off <<= 1)
                s += __shfl_xor(s, off);
            inv4[y] = 1.f / s;
        }
    }

    // ---- phase 3: g[i][head*64+c] = inv[i] * sum_j alpha[i][j]*xl[j][c] --
    {
        const int c0 = j0;                // channel tile = tj
        float oa[4][4] = {};
        for (int jb = 0; jb < 16; ++jb) {
            const int src = ti * 16 + jb; // wave-local (&63 implicit)
            #pragma unroll
            for (int jj = 0; jj < 4; ++jj) {
                const int j = jb * 4 + jj;
                float xv[4];
                *(float4*)xv = *(const float4*)&ar.a.xls[j][c0];
                #pragma unroll
                for (int y = 0; y < 4; ++y) {
                    const float al = __shfl(aa[y][jj], src);
                    #pragma unroll
                    for (int x = 0; x < 4; ++x)
                        oa[y][x] = fmaf(al, xv[x], oa[y][x]);
                }
            }
        }
        #pragma unroll
        for (int y = 0; y < 4; ++y) {
            const float iv = inv4[y];
            float o[4];
            #pragma unroll
            for (int x = 0; x < 4; ++x) o[x] = oa[y][x] * iv;
            float* go = g + (size_t)(gr * NND + i0 + y) * HID_ + head * NCH + c0;
            *(float4*)go = *(float4*)o;
        }
    }
}

// ---------------------------------------------------------------------------
// g + ob -> ELU -> LayerNorm -> + res -> zero unmasked.
// finalSel=0: always write hout (+ optional bf16 mirror hb).
// finalSel=1: hout = d_out holding h0; only overwrite keep-graphs.
__global__ __launch_bounds__(256) void epilogue_kernel(
    const float* __restrict__ g, const float* res,
    const float* __restrict__ ob, const float* __restrict__ lns,
    const float* __restrict__ lnb, const int* __restrict__ msk,
    float* hout, bf16* hb, int finalSel)
{
    const int lane = threadIdx.x & 63;
    const int wave = threadIdx.x >> 6;
    const int m = blockIdx.x * 4 + wave;
    if (finalSel) {
        const int gr = m >> 6;
        const int mv = msk[gr * NND + lane];
        const unsigned long long bal = __ballot(mv != 0);
        if (__popcll(bal) <= 1) return;   // leave h0 rows in d_out
    }
    const float* grow = g + (size_t)m * HID_;
    float v[4];
    float sum = 0.f;
    #pragma unroll
    for (int q = 0; q < 4; ++q) {
        const int c = q * 64 + lane;
        float x = grow[c] + ob[c];
        x = x > 0.f ? x : (__expf(x) - 1.f);   // ELU (alpha=1)
        v[q] = x; sum += x;
    }
    #pragma unroll
    for (int off = 1; off < 64; off <<= 1) sum += __shfl_xor(sum, off);
    const float mu = sum * (1.f / 256.f);
    float vs = 0.f;
    #pragma unroll
    for (int q = 0; q < 4; ++q) { const float d = v[q] - mu; vs += d * d; }
    #pragma unroll
    for (int off = 1; off < 64; off <<= 1) vs += __shfl_xor(vs, off);
    const float rstd = rsqrtf(vs * (1.f / 256.f) + LN_EPS_);
    const int mnode = msk[m];
    const float* rrow = res + (size_t)m * HID_;
    float* ho = hout + (size_t)m * HID_;
    #pragma unroll
    for (int q = 0; q < 4; ++q) {
        const int c = q * 64 + lane;
        float y = (v[q] - mu) * rstd * lns[c] + lnb[c];
        y += rrow[c];
        y = mnode ? y : 0.f;
        ho[c] = y;
        if (hb) hb[(size_t)m * HID_ + c] = __float2bfloat16(y);
    }
}

// ---------------------------------------------------------------------------
extern "C" void kernel_launch(void* const* d_in, const int* in_sizes, int n_in,
                              void* d_out, int out_size, void* d_ws, size_t ws_size,
                              hipStream_t stream) {
    const float* x    = (const float*)d_in[0];
    const float* W_in = (const float*)d_in[2];
    const float* b_in = (const float*)d_in[3];
    const float* Wl   = (const float*)d_in[4];
    const float* bl   = (const float*)d_in[5];
    const float* Wr   = (const float*)d_in[6];
    const float* br   = (const float*)d_in[7];
    const float* att  = (const float*)d_in[8];
    const float* ob   = (const float*)d_in[9];
    const float* lns  = (const float*)d_in[10];
    const float* lnb  = (const float*)d_in[11];
    float* out = (float*)d_out;

    // ws (~21 MB): [mcan 32K][h 8M][gbuf 8M][hxb 4M][WlrT 512K]
    char* w = (char*)d_ws;
    int*   mcan = (int*)w;                      w += 32768;
    float* h    = (float*)w;                    w += (size_t)NROWS * HID_ * 4;
    float* gbuf = (float*)w;                    w += (size_t)NROWS * HID_ * 4;
    bf16*  hxb  = (bf16*)w;                     w += (size_t)NROWS * HID_ * 2;
    bf16*  WlrT = (bf16*)w;                     // [L][512][256]

    // D1: input GEMM + Wl/Wr transposes + mask canon (heterogeneous blocks)
    prep_gemm_in_kernel<<<769, 256, 0, stream>>>(
        x, (const unsigned*)d_in[1], W_in, b_in, Wl, Wr, out, hxb, WlrT, mcan);

    // D2: layer-0 fused GEMM+attention (xl/xr stay on-chip)
    gemm_attn_kernel<<<dim3(NH, BT_G), 256, 0, stream>>>(
        hxb, WlrT, bl, br, att, mcan, gbuf);

    // D3: layer-0 epilogue (writes fp32 h + bf16 hxb)
    epilogue_kernel<<<NROWS / 4, 256, 0, stream>>>(
        gbuf, out, ob, lns, lnb, mcan, h, hxb, 0);

    // D4: layer-1 fused GEMM+attention
    gemm_attn_kernel<<<dim3(NH, BT_G), 256, 0, stream>>>(
        hxb, WlrT + (size_t)512 * HID_, bl + HID_, br + HID_,
        att + NH * NCH, mcan, gbuf);

    // D5: final epilogue with keep-graph select
    epilogue_kernel<<<NROWS / 4, 256, 0, stream>>>(
        gbuf, h, ob + HID_, lns + HID_, lnb + HID_, mcan,
        out, (bf16*)nullptr, 1);

    (void)in_sizes; (void)n_in; (void)out_size; (void)ws_size;
}

// Round 10
// 168.596 us; speedup vs baseline: 1.1835x; 1.1835x over previous
//
#include <hip/hip_runtime.h>
#include <hip/hip_bf16.h>

// Problem constants (B=2,T=64,N=64,D_IN=512,HID=256,L=2,H=4,C=64)
#define BT_G   128
#define NND    64
#define D_IN_  512
#define HID_   256
#define NH     4
#define NCH    64
#define NROWS  8192
#define LN_EPS_    1e-5f

typedef __hip_bfloat16 bf16;
typedef __attribute__((ext_vector_type(8))) short short8;   // 8 bf16 = 4 VGPRs
typedef __attribute__((ext_vector_type(4))) float float4v;  // MFMA C/D

// ---------------------------------------------------------------------------
// Dispatch 1 (heterogeneous, 769 blocks):
//   bid <  512 : input GEMM h0 = x @ W_in^T + b_in (64x64 tile, BK=64),
//                transposing W_in tiles in-staging (no WTin buffer).
//   bid <  768 : Wl/Wr -> WlrT transposes (consumed by later dispatches).
//   bid == 768 : mask canonicalize -> mcan.
union PrepArena {
    float t[32][33];
    struct { bf16 As[64 * 72]; bf16 Bs[64 * 72]; } g;
    int flags[4];
};

__global__ __launch_bounds__(256) void prep_gemm_in_kernel(
    const float* __restrict__ x, const unsigned* __restrict__ mw,
    const float* __restrict__ W_in, const float* __restrict__ b_in,
    const float* __restrict__ Wl, const float* __restrict__ Wr,
    float* __restrict__ Cf, bf16* __restrict__ Cb16,
    bf16* __restrict__ WlrT, int* __restrict__ mout)
{
    __shared__ PrepArena ar;
    const int tid = threadIdx.x;
    const int bid = blockIdx.x;

    if (bid < 512) {
        bf16* As = ar.g.As;
        bf16* Bs = ar.g.Bs;
        const int wave = tid >> 6, lane = tid & 63;
        const int quad = lane >> 4, l16 = lane & 15;
        const int m0 = (bid >> 2) * 64, n0 = (bid & 3) * 64;
        const int wm = (wave & 1) * 32, wn = (wave >> 1) * 32;
        float4v acc[2][2] = {};
        const int r  = tid >> 2;
        const int cq = (tid & 3) * 16;
        for (int k0 = 0; k0 < D_IN_; k0 += 64) {
            const float* sa = x + (size_t)(m0 + r) * D_IN_ + k0 + cq;
            const float4 f0 = *(const float4*)(sa);
            const float4 f1 = *(const float4*)(sa + 4);
            const float4 f2 = *(const float4*)(sa + 8);
            const float4 f3 = *(const float4*)(sa + 12);
            // B-tile: Bs[n][k] = bf16(W_in[k0+k][n0+n]); read rows, scatter.
            const float* sw = W_in + (size_t)(k0 + r) * HID_ + n0 + cq;
            float wv[16];
            *(float4*)(wv)      = *(const float4*)(sw);
            *(float4*)(wv + 4)  = *(const float4*)(sw + 4);
            *(float4*)(wv + 8)  = *(const float4*)(sw + 8);
            *(float4*)(wv + 12) = *(const float4*)(sw + 12);
            union { bf16 hh[16]; float4 v[2]; } u;
            u.hh[0]=__float2bfloat16(f0.x); u.hh[1]=__float2bfloat16(f0.y);
            u.hh[2]=__float2bfloat16(f0.z); u.hh[3]=__float2bfloat16(f0.w);
            u.hh[4]=__float2bfloat16(f1.x); u.hh[5]=__float2bfloat16(f1.y);
            u.hh[6]=__float2bfloat16(f1.z); u.hh[7]=__float2bfloat16(f1.w);
            u.hh[8]=__float2bfloat16(f2.x); u.hh[9]=__float2bfloat16(f2.y);
            u.hh[10]=__float2bfloat16(f2.z); u.hh[11]=__float2bfloat16(f2.w);
            u.hh[12]=__float2bfloat16(f3.x); u.hh[13]=__float2bfloat16(f3.y);
            u.hh[14]=__float2bfloat16(f3.z); u.hh[15]=__float2bfloat16(f3.w);
            __syncthreads();
            *(float4*)(&As[r * 72 + cq])     = u.v[0];
            *(float4*)(&As[r * 72 + cq + 8]) = u.v[1];
            #pragma unroll
            for (int j = 0; j < 16; ++j)
                Bs[(cq + j) * 72 + r] = __float2bfloat16(wv[j]);
            __syncthreads();
            #pragma unroll
            for (int kk = 0; kk < 64; kk += 32) {
                short8 af[2], bf2[2];
                #pragma unroll
                for (int mi = 0; mi < 2; ++mi)
                    af[mi] = *(const short8*)(&As[(wm + mi * 16 + l16) * 72 + kk + quad * 8]);
                #pragma unroll
                for (int ni = 0; ni < 2; ++ni)
                    bf2[ni] = *(const short8*)(&Bs[(wn + ni * 16 + l16) * 72 + kk + quad * 8]);
                #pragma unroll
                for (int mi = 0; mi < 2; ++mi)
                    #pragma unroll
                    for (int ni = 0; ni < 2; ++ni)
                        acc[mi][ni] = __builtin_amdgcn_mfma_f32_16x16x32_bf16(
                            af[mi], bf2[ni], acc[mi][ni], 0, 0, 0);
            }
        }
        #pragma unroll
        for (int ni = 0; ni < 2; ++ni) {
            const int col = n0 + wn + ni * 16 + l16;
            const float bv = b_in[col];
            #pragma unroll
            for (int mi = 0; mi < 2; ++mi)
                #pragma unroll
                for (int rr = 0; rr < 4; ++rr) {
                    const int row = m0 + wm + mi * 16 + quad * 4 + rr;
                    const float v = acc[mi][ni][rr] + bv;
                    Cf[(size_t)row * HID_ + col] = v;
                    Cb16[(size_t)row * HID_ + col] = __float2bfloat16(v);
                }
        }
    } else if (bid < 768) {
        const int q = bid - 512;
        const int z4 = q >> 6;                 // 0,1: Wl li ; 2,3: Wr li
        const int s = q & 63;
        const int n0 = (s & 7) * 32, k0 = (s >> 3) * 32;
        const float* src = (z4 < 2) ? (Wl + z4 * 65536) : (Wr + (z4 - 2) * 65536);
        bf16* dst = WlrT + ((z4 < 2) ? (size_t)z4 * 131072
                                     : (size_t)(z4 - 2) * 131072 + 65536);
        const int tx = tid & 31, ty = tid >> 5;
        #pragma unroll
        for (int i = 0; i < 4; ++i)
            ar.t[ty + 8 * i][tx] = src[(size_t)(k0 + ty + 8 * i) * 256 + n0 + tx];
        __syncthreads();
        #pragma unroll
        for (int i = 0; i < 4; ++i)
            dst[(size_t)(n0 + ty + 8 * i) * 256 + k0 + tx] =
                __float2bfloat16(ar.t[tx][ty + 8 * i]);
    } else {
        int* fl = ar.flags;
        if (tid == 0) { fl[0] = 1; fl[1] = 1; fl[2] = 1; fl[3] = 1; }
        __syncthreads();
        int aI = 1, aF = 1, aB = 1, aC = 1;
        for (int i = tid; i < 2048; i += 256) {   // 8 KB probe — safe all layouts
            const unsigned w2 = mw[i];
            aI &= (w2 <= 1u);
            aF &= (w2 == 0u || w2 == 0x3F800000u);
            const unsigned lo = w2 & 0xFFFFu, hi = w2 >> 16;
            aB &= ((lo == 0u || lo == 0x3F80u) && (hi == 0u || hi == 0x3F80u));
            aC &= (((w2 | (w2 >> 8) | (w2 >> 16) | (w2 >> 24)) & 0xFEu) == 0u);
        }
        if (!aI) atomicAnd(&fl[0], 0);
        if (!aF) atomicAnd(&fl[1], 0);
        if (!aB) atomicAnd(&fl[2], 0);
        if (!aC) atomicAnd(&fl[3], 0);
        __syncthreads();
        const int layout = (fl[0] || fl[1]) ? 0 : (fl[2] ? 2 : (fl[3] ? 3 : 0));
        for (int i = tid; i < NROWS; i += 256) {
            int v;
            if (layout == 2)      v = (((const unsigned short*)mw)[i] != 0);
            else if (layout == 3) v = (((const unsigned char*)mw)[i] != 0);
            else                  v = (mw[i] != 0u);
            mout[i] = v;
        }
    }
}

// ---------------------------------------------------------------------------
// Fused xl|xr GEMM + GATv2 attention per (head, graph): 512 blocks.
// GEMM: 64 rows (one graph) x 128 cols (xl head-cols | xr head-cols), K=256,
// accumulated in registers with the exact gemm_mfma k-order. acc + bias is
// scattered straight into the attention LDS layouts (xls/xlsT/xrsT) — xl/xr
// never touch global memory. Then the r7-verified register-softmax attention
// (one barrier) computes g for this (graph, head).
// C-fragment mapping (verified since round 0): row=wm+mi*16+quad*4+rr,
// col=wn+ni*16+l16. Waves 0,1 (wn=0) own xl cols; waves 2,3 (wn=64) own xr.
union FusedArena {
    struct { bf16 As[64 * 72]; bf16 Bs[128 * 72]; } g;      // 27.6 KB
    struct { float xls[64][68], xlsT[64][68], xrsT[64][68]; } a;  // 52.2 KB
};

__global__ __launch_bounds__(256) void gemm_attn_kernel(
    const bf16* __restrict__ hxbA, const bf16* __restrict__ WlrTl,
    const float* __restrict__ bll, const float* __restrict__ brl,
    const float* __restrict__ attl, const int* __restrict__ msk,
    float* __restrict__ g)
{
    __shared__ FusedArena ar;
    __shared__ float av[64];
    __shared__ int   ms[64];

    const int tid  = threadIdx.x;
    const int head = blockIdx.x, gr = blockIdx.y;
    const int wave = tid >> 6, lane = tid & 63;
    const int quad = lane >> 4, l16 = lane & 15;
    const int wm = (wave & 1) * 32;        // row offset (graph node)
    const int wn = (wave >> 1) * 64;       // col offset: 0 = xl, 64 = xr
    float4v acc[2][4] = {};

    // ---- GEMM: C[64][128] = hxb[gr rows][256] @ B^T + bias ---------------
    {
        bf16* As = ar.g.As;
        bf16* Bs = ar.g.Bs;
        const int rA  = tid >> 2;            // 0..63
        const int cqA = (tid & 3) * 16;
        const int rB  = tid >> 1;            // 0..127
        const int cqB = (tid & 1) * 32;
        // B-panel source row in WlrT: xl j<64 -> head*64+j ; xr -> 256+head*64+j
        const int srcB = (rB < 64) ? (head * NCH + rB) : (256 + head * NCH + rB - 64);
        for (int k0 = 0; k0 < HID_; k0 += 64) {
            const bf16* sa = hxbA + (size_t)(gr * NND + rA) * HID_ + k0 + cqA;
            const float4 a0 = *(const float4*)(sa);
            const float4 a1 = *(const float4*)(sa + 8);
            const bf16* sb = WlrTl + (size_t)srcB * HID_ + k0 + cqB;
            const float4 b0 = *(const float4*)(sb);
            const float4 b1 = *(const float4*)(sb + 8);
            const float4 b2 = *(const float4*)(sb + 16);
            const float4 b3 = *(const float4*)(sb + 24);
            __syncthreads();
            *(float4*)(&As[rA * 72 + cqA])      = a0;
            *(float4*)(&As[rA * 72 + cqA + 8])  = a1;
            *(float4*)(&Bs[rB * 72 + cqB])      = b0;
            *(float4*)(&Bs[rB * 72 + cqB + 8])  = b1;
            *(float4*)(&Bs[rB * 72 + cqB + 16]) = b2;
            *(float4*)(&Bs[rB * 72 + cqB + 24]) = b3;
            __syncthreads();
            #pragma unroll
            for (int kk = 0; kk < 64; kk += 32) {
                short8 af[2], bf2[4];
                #pragma unroll
                for (int mi = 0; mi < 2; ++mi)
                    af[mi] = *(const short8*)(&As[(wm + mi * 16 + l16) * 72 + kk + quad * 8]);
                #pragma unroll
                for (int ni = 0; ni < 4; ++ni)
                    bf2[ni] = *(const short8*)(&Bs[(wn + ni * 16 + l16) * 72 + kk + quad * 8]);
                #pragma unroll
                for (int mi = 0; mi < 2; ++mi)
                    #pragma unroll
                    for (int ni = 0; ni < 4; ++ni)
                        acc[mi][ni] = __builtin_amdgcn_mfma_f32_16x16x32_bf16(
                            af[mi], bf2[ni], acc[mi][ni], 0, 0, 0);
            }
        }
    }
    __syncthreads();   // all As/Bs reads done before arena reuse

    // ---- scatter acc (+bias) into attention layouts ----------------------
    {
        const bool xlW = (wn == 0);
        const float* bp = xlW ? bll : brl;
        float bias[4];
        #pragma unroll
        for (int ni = 0; ni < 4; ++ni)
            bias[ni] = bp[head * NCH + ni * 16 + l16];
        #pragma unroll
        for (int mi = 0; mi < 2; ++mi)
            #pragma unroll
            for (int ni = 0; ni < 4; ++ni)
                #pragma unroll
                for (int rr = 0; rr < 4; ++rr) {
                    const int row = wm + mi * 16 + quad * 4 + rr;   // node
                    const int c   = ni * 16 + l16;                  // channel
                    const float v = acc[mi][ni][rr] + bias[ni];
                    if (xlW) {
                        ar.a.xls[row][c] = v;
                        ar.a.xlsT[c][row] = v;
                    } else {
                        ar.a.xrsT[c][row] = v;
                    }
                }
        if (tid < 64) {
            av[tid] = attl[head * NCH + tid];
            ms[tid] = msk[gr * NND + tid];
        }
    }
    __syncthreads();   // the only attention barrier

    // ---- phase 1: abs-sum + P/Q register accumulation (r7-verified) ------
    const int ti = tid >> 4, tj = tid & 15;   // 16x16 thread grid
    const int i0 = ti * 4, j0 = tj * 4;       // 4x4 tile
    float aa[4][4] = {};
    float p4[4] = {}, q4[4] = {};
    for (int c = 0; c < 64; ++c) {
        const float a = av[c];
        float xr4[4], xl4[4];
        *(float4*)xr4 = *(const float4*)&ar.a.xrsT[c][i0];
        *(float4*)xl4 = *(const float4*)&ar.a.xlsT[c][j0];
        #pragma unroll
        for (int y = 0; y < 4; ++y) p4[y] = fmaf(a, xr4[y], p4[y]);
        #pragma unroll
        for (int x = 0; x < 4; ++x) q4[x] = fmaf(a, xl4[x], q4[x]);
        #pragma unroll
        for (int y = 0; y < 4; ++y)
            #pragma unroll
            for (int x = 0; x < 4; ++x)
                aa[y][x] = fmaf(a, fabsf(xr4[y] + xl4[x]), aa[y][x]);
    }

    // ---- combine + mask + register softmax (16-lane group reductions) ----
    float inv4[4];
    {
        int mi4[4], mj4[4];
        #pragma unroll
        for (int y = 0; y < 4; ++y) mi4[y] = ms[i0 + y];
        #pragma unroll
        for (int x = 0; x < 4; ++x) mj4[x] = ms[j0 + x];
        #pragma unroll
        for (int y = 0; y < 4; ++y) {
            float e[4];
            #pragma unroll
            for (int x = 0; x < 4; ++x) {
                const float ev = fmaf(0.4f, aa[y][x], 0.6f * (p4[y] + q4[x]));
                const bool allowed = (mi4[y] && mj4[x]) || (i0 + y == j0 + x);
                e[x] = allowed ? ev : -1e9f;
            }
            float m = fmaxf(fmaxf(e[0], e[1]), fmaxf(e[2], e[3]));
            #pragma unroll
            for (int off = 1; off < 16; off <<= 1)
                m = fmaxf(m, __shfl_xor(m, off));
            float s = 0.f;
            #pragma unroll
            for (int x = 0; x < 4; ++x) {
                const float ev = __expf(e[x] - m);
                aa[y][x] = ev;            // unnormalized alpha stays in regs
                s += ev;
            }
            #pragma unroll
            for (int off = 1; off < 16; off <<= 1)
                s += __shfl_xor(s, off);
            inv4[y] = 1.f / s;
        }
    }

    // ---- phase 3: g[i][head*64+c] = inv[i] * sum_j alpha[i][j]*xl[j][c] --
    {
        const int c0 = j0;                // channel tile = tj
        float oa[4][4] = {};
        for (int jb = 0; jb < 16; ++jb) {
            const int src = ti * 16 + jb; // wave-local (&63 implicit)
            #pragma unroll
            for (int jj = 0; jj < 4; ++jj) {
                const int j = jb * 4 + jj;
                float xv[4];
                *(float4*)xv = *(const float4*)&ar.a.xls[j][c0];
                #pragma unroll
                for (int y = 0; y < 4; ++y) {
                    const float al = __shfl(aa[y][jj], src);
                    #pragma unroll
                    for (int x = 0; x < 4; ++x)
                        oa[y][x] = fmaf(al, xv[x], oa[y][x]);
                }
            }
        }
        #pragma unroll
        for (int y = 0; y < 4; ++y) {
            const float iv = inv4[y];
            float o[4];
            #pragma unroll
            for (int x = 0; x < 4; ++x) o[x] = oa[y][x] * iv;
            float* go = g + (size_t)(gr * NND + i0 + y) * HID_ + head * NCH + c0;
            *(float4*)go = *(float4*)o;
        }
    }
}

// ---------------------------------------------------------------------------
// g + ob -> ELU -> LayerNorm -> + res -> zero unmasked.
// finalSel=0: always write hout (+ optional bf16 mirror hb).
// finalSel=1: hout = d_out holding h0; only overwrite keep-graphs.
__global__ __launch_bounds__(256) void epilogue_kernel(
    const float* __restrict__ g, const float* res,
    const float* __restrict__ ob, const float* __restrict__ lns,
    const float* __restrict__ lnb, const int* __restrict__ msk,
    float* hout, bf16* hb, int finalSel)
{
    const int lane = threadIdx.x & 63;
    const int wave = threadIdx.x >> 6;
    const int m = blockIdx.x * 4 + wave;
    if (finalSel) {
        const int gr = m >> 6;
        const int mv = msk[gr * NND + lane];
        const unsigned long long bal = __ballot(mv != 0);
        if (__popcll(bal) <= 1) return;   // leave h0 rows in d_out
    }
    const float* grow = g + (size_t)m * HID_;
    float v[4];
    float sum = 0.f;
    #pragma unroll
    for (int q = 0; q < 4; ++q) {
        const int c = q * 64 + lane;
        float x = grow[c] + ob[c];
        x = x > 0.f ? x : (__expf(x) - 1.f);   // ELU (alpha=1)
        v[q] = x; sum += x;
    }
    #pragma unroll
    for (int off = 1; off < 64; off <<= 1) sum += __shfl_xor(sum, off);
    const float mu = sum * (1.f / 256.f);
    float vs = 0.f;
    #pragma unroll
    for (int q = 0; q < 4; ++q) { const float d = v[q] - mu; vs += d * d; }
    #pragma unroll
    for (int off = 1; off < 64; off <<= 1) vs += __shfl_xor(vs, off);
    const float rstd = rsqrtf(vs * (1.f / 256.f) + LN_EPS_);
    const int mnode = msk[m];
    const float* rrow = res + (size_t)m * HID_;
    float* ho = hout + (size_t)m * HID_;
    #pragma unroll
    for (int q = 0; q < 4; ++q) {
        const int c = q * 64 + lane;
        float y = (v[q] - mu) * rstd * lns[c] + lnb[c];
        y += rrow[c];
        y = mnode ? y : 0.f;
        ho[c] = y;
        if (hb) hb[(size_t)m * HID_ + c] = __float2bfloat16(y);
    }
}

// ---------------------------------------------------------------------------
extern "C" void kernel_launch(void* const* d_in, const int* in_sizes, int n_in,
                              void* d_out, int out_size, void* d_ws, size_t ws_size,
                              hipStream_t stream) {
    const float* x    = (const float*)d_in[0];
    const float* W_in = (const float*)d_in[2];
    const float* b_in = (const float*)d_in[3];
    const float* Wl   = (const float*)d_in[4];
    const float* bl   = (const float*)d_in[5];
    const float* Wr   = (const float*)d_in[6];
    const float* br   = (const float*)d_in[7];
    const float* att  = (const float*)d_in[8];
    const float* ob   = (const float*)d_in[9];
    const float* lns  = (const float*)d_in[10];
    const float* lnb  = (const float*)d_in[11];
    float* out = (float*)d_out;

    // ws (~21 MB): [mcan 32K][h 8M][gbuf 8M][hxb 4M][WlrT 512K]
    char* w = (char*)d_ws;
    int*   mcan = (int*)w;                      w += 32768;
    float* h    = (float*)w;                    w += (size_t)NROWS * HID_ * 4;
    float* gbuf = (float*)w;                    w += (size_t)NROWS * HID_ * 4;
    bf16*  hxb  = (bf16*)w;                     w += (size_t)NROWS * HID_ * 2;
    bf16*  WlrT = (bf16*)w;                     // [L][512][256]

    // D1: input GEMM + Wl/Wr transposes + mask canon (heterogeneous blocks)
    prep_gemm_in_kernel<<<769, 256, 0, stream>>>(
        x, (const unsigned*)d_in[1], W_in, b_in, Wl, Wr, out, hxb, WlrT, mcan);

    // D2: layer-0 fused GEMM+attention (xl/xr stay on-chip)
    gemm_attn_kernel<<<dim3(NH, BT_G), 256, 0, stream>>>(
        hxb, WlrT, bl, br, att, mcan, gbuf);

    // D3: layer-0 epilogue (writes fp32 h + bf16 hxb)
    epilogue_kernel<<<NROWS / 4, 256, 0, stream>>>(
        gbuf, out, ob, lns, lnb, mcan, h, hxb, 0);

    // D4: layer-1 fused GEMM+attention
    gemm_attn_kernel<<<dim3(NH, BT_G), 256, 0, stream>>>(
        hxb, WlrT + (size_t)512 * HID_, bl + HID_, br + HID_,
        att + NH * NCH, mcan, gbuf);

    // D5: final epilogue with keep-graph select
    epilogue_kernel<<<NROWS / 4, 256, 0, stream>>>(
        gbuf, h, ob + HID_, lns + HID_, lnb + HID_, mcan,
        out, (bf16*)nullptr, 1);

    (void)in_sizes; (void)n_in; (void)out_size; (void)ws_size;
}

// Round 11
// 166.132 us; speedup vs baseline: 1.2011x; 1.0148x over previous
//
#include <hip/hip_runtime.h>
#include <hip/hip_bf16.h>

// Problem constants (B=2,T=64,N=64,D_IN=512,HID=256,L=2,H=4,C=64)
#define BT_G   128
#define NND    64
#define D_IN_  512
#define HID_   256
#define NH     4
#define NCH    64
#define NROWS  8192
#define LN_EPS_    1e-5f

typedef __hip_bfloat16 bf16;
typedef __attribute__((ext_vector_type(8))) short short8;   // 8 bf16 = 4 VGPRs
typedef __attribute__((ext_vector_type(4))) float float4v;  // MFMA C/D

// ---------------------------------------------------------------------------
// Dispatch 1 (heterogeneous, 769 blocks):
//   bid <  512 : input GEMM h0 = x @ W_in^T + b_in (64x64 tile, BK=64),
//                transposing W_in tiles in-staging (no WTin buffer).
//                XCD-aware decomposition: m = bid & 127, n = bid >> 7, so the
//                4 blocks sharing an x row-panel have bids {b,b+128,b+256,
//                b+384} — congruent mod 8 — and land on ONE XCD's L2
//                (round-robin dispatch), fetching x once instead of 4x.
//   bid <  768 : Wl/Wr -> WlrT transposes (consumed by later dispatches).
//   bid == 768 : mask canonicalize -> mcan.
union PrepArena {
    float t[32][33];
    struct { bf16 As[64 * 72]; bf16 Bs[64 * 72]; } g;
    int flags[4];
};

__global__ __launch_bounds__(256) void prep_gemm_in_kernel(
    const float* __restrict__ x, const unsigned* __restrict__ mw,
    const float* __restrict__ W_in, const float* __restrict__ b_in,
    const float* __restrict__ Wl, const float* __restrict__ Wr,
    float* __restrict__ Cf, bf16* __restrict__ Cb16,
    bf16* __restrict__ WlrT, int* __restrict__ mout)
{
    __shared__ PrepArena ar;
    const int tid = threadIdx.x;
    const int bid = blockIdx.x;

    if (bid < 512) {
        bf16* As = ar.g.As;
        bf16* Bs = ar.g.Bs;
        const int wave = tid >> 6, lane = tid & 63;
        const int quad = lane >> 4, l16 = lane & 15;
        // XCD-aware: same-m blocks congruent mod 8 -> same XCD L2.
        const int m0 = (bid & 127) * 64, n0 = (bid >> 7) * 64;
        const int wm = (wave & 1) * 32, wn = (wave >> 1) * 32;
        float4v acc[2][2] = {};
        const int r  = tid >> 2;
        const int cq = (tid & 3) * 16;
        for (int k0 = 0; k0 < D_IN_; k0 += 64) {
            const float* sa = x + (size_t)(m0 + r) * D_IN_ + k0 + cq;
            const float4 f0 = *(const float4*)(sa);
            const float4 f1 = *(const float4*)(sa + 4);
            const float4 f2 = *(const float4*)(sa + 8);
            const float4 f3 = *(const float4*)(sa + 12);
            // B-tile: Bs[n][k] = bf16(W_in[k0+k][n0+n]); read rows, scatter.
            const float* sw = W_in + (size_t)(k0 + r) * HID_ + n0 + cq;
            float wv[16];
            *(float4*)(wv)      = *(const float4*)(sw);
            *(float4*)(wv + 4)  = *(const float4*)(sw + 4);
            *(float4*)(wv + 8)  = *(const float4*)(sw + 8);
            *(float4*)(wv + 12) = *(const float4*)(sw + 12);
            union { bf16 hh[16]; float4 v[2]; } u;
            u.hh[0]=__float2bfloat16(f0.x); u.hh[1]=__float2bfloat16(f0.y);
            u.hh[2]=__float2bfloat16(f0.z); u.hh[3]=__float2bfloat16(f0.w);
            u.hh[4]=__float2bfloat16(f1.x); u.hh[5]=__float2bfloat16(f1.y);
            u.hh[6]=__float2bfloat16(f1.z); u.hh[7]=__float2bfloat16(f1.w);
            u.hh[8]=__float2bfloat16(f2.x); u.hh[9]=__float2bfloat16(f2.y);
            u.hh[10]=__float2bfloat16(f2.z); u.hh[11]=__float2bfloat16(f2.w);
            u.hh[12]=__float2bfloat16(f3.x); u.hh[13]=__float2bfloat16(f3.y);
            u.hh[14]=__float2bfloat16(f3.z); u.hh[15]=__float2bfloat16(f3.w);
            __syncthreads();
            *(float4*)(&As[r * 72 + cq])     = u.v[0];
            *(float4*)(&As[r * 72 + cq + 8]) = u.v[1];
            #pragma unroll
            for (int j = 0; j < 16; ++j)
                Bs[(cq + j) * 72 + r] = __float2bfloat16(wv[j]);
            __syncthreads();
            #pragma unroll
            for (int kk = 0; kk < 64; kk += 32) {
                short8 af[2], bf2[2];
                #pragma unroll
                for (int mi = 0; mi < 2; ++mi)
                    af[mi] = *(const short8*)(&As[(wm + mi * 16 + l16) * 72 + kk + quad * 8]);
                #pragma unroll
                for (int ni = 0; ni < 2; ++ni)
                    bf2[ni] = *(const short8*)(&Bs[(wn + ni * 16 + l16) * 72 + kk + quad * 8]);
                #pragma unroll
                for (int mi = 0; mi < 2; ++mi)
                    #pragma unroll
                    for (int ni = 0; ni < 2; ++ni)
                        acc[mi][ni] = __builtin_amdgcn_mfma_f32_16x16x32_bf16(
                            af[mi], bf2[ni], acc[mi][ni], 0, 0, 0);
            }
        }
        #pragma unroll
        for (int ni = 0; ni < 2; ++ni) {
            const int col = n0 + wn + ni * 16 + l16;
            const float bv = b_in[col];
            #pragma unroll
            for (int mi = 0; mi < 2; ++mi)
                #pragma unroll
                for (int rr = 0; rr < 4; ++rr) {
                    const int row = m0 + wm + mi * 16 + quad * 4 + rr;
                    const float v = acc[mi][ni][rr] + bv;
                    Cf[(size_t)row * HID_ + col] = v;
                    Cb16[(size_t)row * HID_ + col] = __float2bfloat16(v);
                }
        }
    } else if (bid < 768) {
        const int q = bid - 512;
        const int z4 = q >> 6;                 // 0,1: Wl li ; 2,3: Wr li
        const int s = q & 63;
        const int n0 = (s & 7) * 32, k0 = (s >> 3) * 32;
        const float* src = (z4 < 2) ? (Wl + z4 * 65536) : (Wr + (z4 - 2) * 65536);
        bf16* dst = WlrT + ((z4 < 2) ? (size_t)z4 * 131072
                                     : (size_t)(z4 - 2) * 131072 + 65536);
        const int tx = tid & 31, ty = tid >> 5;
        #pragma unroll
        for (int i = 0; i < 4; ++i)
            ar.t[ty + 8 * i][tx] = src[(size_t)(k0 + ty + 8 * i) * 256 + n0 + tx];
        __syncthreads();
        #pragma unroll
        for (int i = 0; i < 4; ++i)
            dst[(size_t)(n0 + ty + 8 * i) * 256 + k0 + tx] =
                __float2bfloat16(ar.t[tx][ty + 8 * i]);
    } else {
        int* fl = ar.flags;
        if (tid == 0) { fl[0] = 1; fl[1] = 1; fl[2] = 1; fl[3] = 1; }
        __syncthreads();
        int aI = 1, aF = 1, aB = 1, aC = 1;
        for (int i = tid; i < 2048; i += 256) {   // 8 KB probe — safe all layouts
            const unsigned w2 = mw[i];
            aI &= (w2 <= 1u);
            aF &= (w2 == 0u || w2 == 0x3F800000u);
            const unsigned lo = w2 & 0xFFFFu, hi = w2 >> 16;
            aB &= ((lo == 0u || lo == 0x3F80u) && (hi == 0u || hi == 0x3F80u));
            aC &= (((w2 | (w2 >> 8) | (w2 >> 16) | (w2 >> 24)) & 0xFEu) == 0u);
        }
        if (!aI) atomicAnd(&fl[0], 0);
        if (!aF) atomicAnd(&fl[1], 0);
        if (!aB) atomicAnd(&fl[2], 0);
        if (!aC) atomicAnd(&fl[3], 0);
        __syncthreads();
        const int layout = (fl[0] || fl[1]) ? 0 : (fl[2] ? 2 : (fl[3] ? 3 : 0));
        for (int i = tid; i < NROWS; i += 256) {
            int v;
            if (layout == 2)      v = (((const unsigned short*)mw)[i] != 0);
            else if (layout == 3) v = (((const unsigned char*)mw)[i] != 0);
            else                  v = (mw[i] != 0u);
            mout[i] = v;
        }
    }
}

// ---------------------------------------------------------------------------
// Fused xl|xr GEMM + GATv2 attention per (graph, head): 512 blocks, grid
// (BT_G, NH) — XCD-aware: blockIdx.x = graph, so the 4 heads sharing a
// graph's hxb rows have bids {gr, gr+128, gr+256, gr+384}, congruent mod 8
// -> same XCD L2 -> hxb fetched once per graph instead of 4x.
// GEMM: 64 rows (one graph) x 128 cols (xl head-cols | xr head-cols), K=256,
// accumulated in registers with the exact gemm_mfma k-order. acc + bias is
// scattered straight into the attention LDS layouts (xls/xlsT/xrsT) — xl/xr
// never touch global memory. Then the r7-verified register-softmax attention
// (one barrier) computes g for this (graph, head).
// C-fragment mapping (verified since round 0): row=wm+mi*16+quad*4+rr,
// col=wn+ni*16+l16. Waves 0,1 (wn=0) own xl cols; waves 2,3 (wn=64) own xr.
union FusedArena {
    struct { bf16 As[64 * 72]; bf16 Bs[128 * 72]; } g;      // 27.6 KB
    struct { float xls[64][68], xlsT[64][68], xrsT[64][68]; } a;  // 52.2 KB
};

__global__ __launch_bounds__(256) void gemm_attn_kernel(
    const bf16* __restrict__ hxbA, const bf16* __restrict__ WlrTl,
    const float* __restrict__ bll, const float* __restrict__ brl,
    const float* __restrict__ attl, const int* __restrict__ msk,
    float* __restrict__ g)
{
    __shared__ FusedArena ar;
    __shared__ float av[64];
    __shared__ int   ms[64];

    const int tid  = threadIdx.x;
    const int gr = blockIdx.x, head = blockIdx.y;   // XCD-aware order
    const int wave = tid >> 6, lane = tid & 63;
    const int quad = lane >> 4, l16 = lane & 15;
    const int wm = (wave & 1) * 32;        // row offset (graph node)
    const int wn = (wave >> 1) * 64;       // col offset: 0 = xl, 64 = xr
    float4v acc[2][4] = {};

    // ---- GEMM: C[64][128] = hxb[gr rows][256] @ B^T + bias ---------------
    {
        bf16* As = ar.g.As;
        bf16* Bs = ar.g.Bs;
        const int rA  = tid >> 2;            // 0..63
        const int cqA = (tid & 3) * 16;
        const int rB  = tid >> 1;            // 0..127
        const int cqB = (tid & 1) * 32;
        // B-panel source row in WlrT: xl j<64 -> head*64+j ; xr -> 256+head*64+j
        const int srcB = (rB < 64) ? (head * NCH + rB) : (256 + head * NCH + rB - 64);
        for (int k0 = 0; k0 < HID_; k0 += 64) {
            const bf16* sa = hxbA + (size_t)(gr * NND + rA) * HID_ + k0 + cqA;
            const float4 a0 = *(const float4*)(sa);
            const float4 a1 = *(const float4*)(sa + 8);
            const bf16* sb = WlrTl + (size_t)srcB * HID_ + k0 + cqB;
            const float4 b0 = *(const float4*)(sb);
            const float4 b1 = *(const float4*)(sb + 8);
            const float4 b2 = *(const float4*)(sb + 16);
            const float4 b3 = *(const float4*)(sb + 24);
            __syncthreads();
            *(float4*)(&As[rA * 72 + cqA])      = a0;
            *(float4*)(&As[rA * 72 + cqA + 8])  = a1;
            *(float4*)(&Bs[rB * 72 + cqB])      = b0;
            *(float4*)(&Bs[rB * 72 + cqB + 8])  = b1;
            *(float4*)(&Bs[rB * 72 + cqB + 16]) = b2;
            *(float4*)(&Bs[rB * 72 + cqB + 24]) = b3;
            __syncthreads();
            #pragma unroll
            for (int kk = 0; kk < 64; kk += 32) {
                short8 af[2], bf2[4];
                #pragma unroll
                for (int mi = 0; mi < 2; ++mi)
                    af[mi] = *(const short8*)(&As[(wm + mi * 16 + l16) * 72 + kk + quad * 8]);
                #pragma unroll
                for (int ni = 0; ni < 4; ++ni)
                    bf2[ni] = *(const short8*)(&Bs[(wn + ni * 16 + l16) * 72 + kk + quad * 8]);
                #pragma unroll
                for (int mi = 0; mi < 2; ++mi)
                    #pragma unroll
                    for (int ni = 0; ni < 4; ++ni)
                        acc[mi][ni] = __builtin_amdgcn_mfma_f32_16x16x32_bf16(
                            af[mi], bf2[ni], acc[mi][ni], 0, 0, 0);
            }
        }
    }
    __syncthreads();   // all As/Bs reads done before arena reuse

    // ---- scatter acc (+bias) into attention layouts ----------------------
    {
        const bool xlW = (wn == 0);
        const float* bp = xlW ? bll : brl;
        float bias[4];
        #pragma unroll
        for (int ni = 0; ni < 4; ++ni)
            bias[ni] = bp[head * NCH + ni * 16 + l16];
        #pragma unroll
        for (int mi = 0; mi < 2; ++mi)
            #pragma unroll
            for (int ni = 0; ni < 4; ++ni)
                #pragma unroll
                for (int rr = 0; rr < 4; ++rr) {
                    const int row = wm + mi * 16 + quad * 4 + rr;   // node
                    const int c   = ni * 16 + l16;                  // channel
                    const float v = acc[mi][ni][rr] + bias[ni];
                    if (xlW) {
                        ar.a.xls[row][c] = v;
                        ar.a.xlsT[c][row] = v;
                    } else {
                        ar.a.xrsT[c][row] = v;
                    }
                }
        if (tid < 64) {
            av[tid] = attl[head * NCH + tid];
            ms[tid] = msk[gr * NND + tid];
        }
    }
    __syncthreads();   // the only attention barrier

    // ---- phase 1: abs-sum + P/Q register accumulation (r7-verified) ------
    const int ti = tid >> 4, tj = tid & 15;   // 16x16 thread grid
    const int i0 = ti * 4, j0 = tj * 4;       // 4x4 tile
    float aa[4][4] = {};
    float p4[4] = {}, q4[4] = {};
    for (int c = 0; c < 64; ++c) {
        const float a = av[c];
        float xr4[4], xl4[4];
        *(float4*)xr4 = *(const float4*)&ar.a.xrsT[c][i0];
        *(float4*)xl4 = *(const float4*)&ar.a.xlsT[c][j0];
        #pragma unroll
        for (int y = 0; y < 4; ++y) p4[y] = fmaf(a, xr4[y], p4[y]);
        #pragma unroll
        for (int x = 0; x < 4; ++x) q4[x] = fmaf(a, xl4[x], q4[x]);
        #pragma unroll
        for (int y = 0; y < 4; ++y)
            #pragma unroll
            for (int x = 0; x < 4; ++x)
                aa[y][x] = fmaf(a, fabsf(xr4[y] + xl4[x]), aa[y][x]);
    }

    // ---- combine + mask + register softmax (16-lane group reductions) ----
    float inv4[4];
    {
        int mi4[4], mj4[4];
        #pragma unroll
        for (int y = 0; y < 4; ++y) mi4[y] = ms[i0 + y];
        #pragma unroll
        for (int x = 0; x < 4; ++x) mj4[x] = ms[j0 + x];
        #pragma unroll
        for (int y = 0; y < 4; ++y) {
            float e[4];
            #pragma unroll
            for (int x = 0; x < 4; ++x) {
                const float ev = fmaf(0.4f, aa[y][x], 0.6f * (p4[y] + q4[x]));
                const bool allowed = (mi4[y] && mj4[x]) || (i0 + y == j0 + x);
                e[x] = allowed ? ev : -1e9f;
            }
            float m = fmaxf(fmaxf(e[0], e[1]), fmaxf(e[2], e[3]));
            #pragma unroll
            for (int off = 1; off < 16; off <<= 1)
                m = fmaxf(m, __shfl_xor(m, off));
            float s = 0.f;
            #pragma unroll
            for (int x = 0; x < 4; ++x) {
                const float ev = __expf(e[x] - m);
                aa[y][x] = ev;            // unnormalized alpha stays in regs
                s += ev;
            }
            #pragma unroll
            for (int off = 1; off < 16; off <<= 1)
                s += __shfl_xor(s, off);
            inv4[y] = 1.f / s;
        }
    }

    // ---- phase 3: g[i][head*64+c] = inv[i] * sum_j alpha[i][j]*xl[j][c] --
    {
        const int c0 = j0;                // channel tile = tj
        float oa[4][4] = {};
        for (int jb = 0; jb < 16; ++jb) {
            const int src = ti * 16 + jb; // wave-local (&63 implicit)
            #pragma unroll
            for (int jj = 0; jj < 4; ++jj) {
                const int j = jb * 4 + jj;
                float xv[4];
                *(float4*)xv = *(const float4*)&ar.a.xls[j][c0];
                #pragma unroll
                for (int y = 0; y < 4; ++y) {
                    const float al = __shfl(aa[y][jj], src);
                    #pragma unroll
                    for (int x = 0; x < 4; ++x)
                        oa[y][x] = fmaf(al, xv[x], oa[y][x]);
                }
            }
        }
        #pragma unroll
        for (int y = 0; y < 4; ++y) {
            const float iv = inv4[y];
            float o[4];
            #pragma unroll
            for (int x = 0; x < 4; ++x) o[x] = oa[y][x] * iv;
            float* go = g + (size_t)(gr * NND + i0 + y) * HID_ + head * NCH + c0;
            *(float4*)go = *(float4*)o;
        }
    }
}

// ---------------------------------------------------------------------------
// g + ob -> ELU -> LayerNorm -> + res -> zero unmasked.
// finalSel=0: always write hout (+ optional bf16 mirror hb).
// finalSel=1: hout = d_out holding h0; only overwrite keep-graphs.
__global__ __launch_bounds__(256) void epilogue_kernel(
    const float* __restrict__ g, const float* res,
    const float* __restrict__ ob, const float* __restrict__ lns,
    const float* __restrict__ lnb, const int* __restrict__ msk,
    float* hout, bf16* hb, int finalSel)
{
    const int lane = threadIdx.x & 63;
    const int wave = threadIdx.x >> 6;
    const int m = blockIdx.x * 4 + wave;
    if (finalSel) {
        const int gr = m >> 6;
        const int mv = msk[gr * NND + lane];
        const unsigned long long bal = __ballot(mv != 0);
        if (__popcll(bal) <= 1) return;   // leave h0 rows in d_out
    }
    const float* grow = g + (size_t)m * HID_;
    float v[4];
    float sum = 0.f;
    #pragma unroll
    for (int q = 0; q < 4; ++q) {
        const int c = q * 64 + lane;
        float x = grow[c] + ob[c];
        x = x > 0.f ? x : (__expf(x) - 1.f);   // ELU (alpha=1)
        v[q] = x; sum += x;
    }
    #pragma unroll
    for (int off = 1; off < 64; off <<= 1) sum += __shfl_xor(sum, off);
    const float mu = sum * (1.f / 256.f);
    float vs = 0.f;
    #pragma unroll
    for (int q = 0; q < 4; ++q) { const float d = v[q] - mu; vs += d * d; }
    #pragma unroll
    for (int off = 1; off < 64; off <<= 1) vs += __shfl_xor(vs, off);
    const float rstd = rsqrtf(vs * (1.f / 256.f) + LN_EPS_);
    const int mnode = msk[m];
    const float* rrow = res + (size_t)m * HID_;
    float* ho = hout + (size_t)m * HID_;
    #pragma unroll
    for (int q = 0; q < 4; ++q) {
        const int c = q * 64 + lane;
        float y = (v[q] - mu) * rstd * lns[c] + lnb[c];
        y += rrow[c];
        y = mnode ? y : 0.f;
        ho[c] = y;
        if (hb) hb[(size_t)m * HID_ + c] = __float2bfloat16(y);
    }
}

// ---------------------------------------------------------------------------
extern "C" void kernel_launch(void* const* d_in, const int* in_sizes, int n_in,
                              void* d_out, int out_size, void* d_ws, size_t ws_size,
                              hipStream_t stream) {
    const float* x    = (const float*)d_in[0];
    const float* W_in = (const float*)d_in[2];
    const float* b_in = (const float*)d_in[3];
    const float* Wl   = (const float*)d_in[4];
    const float* bl   = (const float*)d_in[5];
    const float* Wr   = (const float*)d_in[6];
    const float* br   = (const float*)d_in[7];
    const float* att  = (const float*)d_in[8];
    const float* ob   = (const float*)d_in[9];
    const float* lns  = (const float*)d_in[10];
    const float* lnb  = (const float*)d_in[11];
    float* out = (float*)d_out;

    // ws (~21 MB): [mcan 32K][h 8M][gbuf 8M][hxb 4M][WlrT 512K]
    char* w = (char*)d_ws;
    int*   mcan = (int*)w;                      w += 32768;
    float* h    = (float*)w;                    w += (size_t)NROWS * HID_ * 4;
    float* gbuf = (float*)w;                    w += (size_t)NROWS * HID_ * 4;
    bf16*  hxb  = (bf16*)w;                     w += (size_t)NROWS * HID_ * 2;
    bf16*  WlrT = (bf16*)w;                     // [L][512][256]

    // D1: input GEMM + Wl/Wr transposes + mask canon (heterogeneous blocks)
    prep_gemm_in_kernel<<<769, 256, 0, stream>>>(
        x, (const unsigned*)d_in[1], W_in, b_in, Wl, Wr, out, hxb, WlrT, mcan);

    // D2: layer-0 fused GEMM+attention (xl/xr stay on-chip); grid (graph, head)
    gemm_attn_kernel<<<dim3(BT_G, NH), 256, 0, stream>>>(
        hxb, WlrT, bl, br, att, mcan, gbuf);

    // D3: layer-0 epilogue (writes fp32 h + bf16 hxb)
    epilogue_kernel<<<NROWS / 4, 256, 0, stream>>>(
        gbuf, out, ob, lns, lnb, mcan, h, hxb, 0);

    // D4: layer-1 fused GEMM+attention
    gemm_attn_kernel<<<dim3(BT_G, NH), 256, 0, stream>>>(
        hxb, WlrT + (size_t)512 * HID_, bl + HID_, br + HID_,
        att + NH * NCH, mcan, gbuf);

    // D5: final epilogue with keep-graph select
    epilogue_kernel<<<NROWS / 4, 256, 0, stream>>>(
        gbuf, h, ob + HID_, lns + HID_, lnb + HID_, mcan,
        out, (bf16*)nullptr, 1);

    (void)in_sizes; (void)n_in; (void)out_size; (void)ws_size;
}